// Round 11
// baseline (125.435 us; speedup 1.0000x reference)
//
#include <hip/hip_runtime.h>
#include <hip/hip_bf16.h>
#include <math.h>

#define B    4
#define QL   2048
#define KVL  2048
#define CQ   256
#define CKV  256
#define CH   32
#define NH   8
#define DM   256   // NH*CH
#define QB   128   // q rows per fattn block (4 q-subtiles x 32)
#define KVB  128   // kv strip per iteration
#define NSTRIP (KVL / KVB)   // 16

typedef __attribute__((ext_vector_type(8)))  short short8;   // 8 x bf16 (4 VGPR)
typedef __attribute__((ext_vector_type(4)))  float f32x4;
typedef __attribute__((ext_vector_type(16))) float f32x16;
typedef __attribute__((ext_vector_type(4)))  unsigned int u32x4;

static __device__ __forceinline__ short f2bf(float x) {
    __hip_bfloat16 h = __float2bfloat16(x);
    return __builtin_bit_cast(short, h);
}
// pack two f32 -> u32 of 2 bf16 (compiler fuses to v_cvt_pk_bf16_f32)
static __device__ __forceinline__ unsigned int pkbf(float lo, float hi) {
    return (unsigned int)(unsigned short)f2bf(lo) |
           ((unsigned int)(unsigned short)f2bf(hi) << 16);
}

// ---------------------------------------------------------------------------
// prep: fp32 -> bf16 copy (8 elems/thread)
// ---------------------------------------------------------------------------
__global__ __launch_bounds__(256) void prep_cvt(
    const float* __restrict__ src, short* __restrict__ dst, int n8)
{
    int i = blockIdx.x * 256 + threadIdx.x;
    if (i >= n8) return;
    const float4* s = (const float4*)src + (size_t)i * 2;
    float4 a = s[0], b = s[1];
    short8 o = { f2bf(a.x), f2bf(a.y), f2bf(a.z), f2bf(a.w),
                 f2bf(b.x), f2bf(b.y), f2bf(b.z), f2bf(b.w) };
    *((short8*)dst + i) = o;
}

// ---------------------------------------------------------------------------
// prep: W [K][N] fp32 -> W^T [N][K] bf16, 32x32 LDS tiles
// ---------------------------------------------------------------------------
__global__ __launch_bounds__(256) void prep_wT(
    const float* __restrict__ w, short* __restrict__ wt, int K, int N)
{
    __shared__ float tile[32][33];
    const int bx = blockIdx.x * 32;            // n
    const int by = blockIdx.y * 32;            // k
    const int tx = threadIdx.x & 31, ty = threadIdx.x >> 5;
    #pragma unroll
    for (int i = 0; i < 32; i += 8)
        tile[ty + i][tx] = w[(size_t)(by + ty + i) * N + bx + tx];
    __syncthreads();
    #pragma unroll
    for (int i = 0; i < 32; i += 8)
        wt[(size_t)(bx + ty + i) * K + by + tx] = f2bf(tile[tx][ty + i]);
}

// ---------------------------------------------------------------------------
// bf16 MFMA GEMM (unchanged): A [M][K] bf16, BT [N][K] bf16.
// 64x64 tile, 4 waves (2x2 of 32x32), BK=32.
// ---------------------------------------------------------------------------
__global__ __launch_bounds__(256) void gemm_mfma(
    const short* __restrict__ A, const short* __restrict__ BT,
    const float* __restrict__ bias, float* __restrict__ outf,
    short* __restrict__ outb,
    int M, int N, int K, float alpha, int mode)
{
    __shared__ __align__(16) short As[64][40];
    __shared__ __align__(16) short Bs[64][40];

    const int t   = threadIdx.x;
    const int m0  = blockIdx.y * 64, n0 = blockIdx.x * 64;
    const int lane = t & 63, w = t >> 6;
    const int c16 = lane & 15, g = lane >> 4;
    const int wm  = (w & 1) * 32, wn = (w >> 1) * 32;
    const int lr  = t >> 2, lc = (t & 3) * 8;

    f32x4 acc[2][2] = {};

    for (int k0 = 0; k0 < K; k0 += 32) {
        __syncthreads();
        *(short8*)&As[lr][lc] = *(const short8*)(A  + (size_t)(m0 + lr) * K + k0 + lc);
        *(short8*)&Bs[lr][lc] = *(const short8*)(BT + (size_t)(n0 + lr) * K + k0 + lc);
        __syncthreads();

        short8 af[2], bf[2];
        #pragma unroll
        for (int i = 0; i < 2; i++) {
            af[i] = *(const short8*)&As[wm + i * 16 + c16][g * 8];
            bf[i] = *(const short8*)&Bs[wn + i * 16 + c16][g * 8];
        }
        #pragma unroll
        for (int i = 0; i < 2; i++)
            #pragma unroll
            for (int j = 0; j < 2; j++)
                acc[i][j] = __builtin_amdgcn_mfma_f32_16x16x32_bf16(af[i], bf[j], acc[i][j], 0, 0, 0);
    }

    #pragma unroll
    for (int i = 0; i < 2; i++) {
        #pragma unroll
        for (int j = 0; j < 2; j++) {
            #pragma unroll
            for (int r = 0; r < 4; r++) {
                int m = m0 + wm + i * 16 + g * 4 + r;
                int n = n0 + wn + j * 16 + c16;
                float v = acc[i][j][r] * alpha;
                if (mode == 0) {
                    outf[(size_t)m * N + n] = v + (bias ? bias[n] : 0.0f);
                } else {
                    int bb = m >> 11, l = m & 2047;
                    int hh = n >> 5,  cc = n & 31;
                    if (mode == 1)
                        outb[(((size_t)bb * NH + hh) * QL + l) * CH + cc] = f2bf(v);
                    else
                        outb[(((size_t)bb * NH + hh) * CH + cc) * (size_t)KVL + l] = f2bf(v);
                }
            }
        }
    }
}

// ---------------------------------------------------------------------------
// Flash attention, R11 = R10 (intra-block KV-split, 8 waves = 4 q-subtiles x
// 2 kv-halves, 32x32x16 MFMA, swapped QK^T, in-register P, static-max exp2
// softmax, C-in bias fold) with the SPILL FIXED:
//   - amdgpu_waves_per_eu(4): VGPR cap 128 (R10's heuristic picked 8/EU -> 64
//     -> scratch spill -> +60 MB FETCH). Grid is 2 blocks/CU so 4 waves/EU is
//     exactly the reachable occupancy.
//   - exp->pack fused per 4-reg group: p[] never lives as 16 floats.
// D-map (m74/m101): row=(r&3)+8*(r>>2)+4*(lane>>5), col=lane&31.
// ---------------------------------------------------------------------------
__global__ __launch_bounds__(512)
__attribute__((amdgpu_waves_per_eu(4)))
void fattn(
    const short* __restrict__ qbf, const short* __restrict__ kbf,
    const short* __restrict__ vtb, const float* __restrict__ mask,
    const float* __restrict__ bias, short* __restrict__ aob)
{
    __shared__ __align__(16) short Kl[2][KVB * 32];     // 16 KB, swizzled [kv][ch]
    __shared__ __align__(16) short Vl[2][32 * KVB];     // 16 KB, swizzled [ch][kv]
    __shared__ __align__(16) float Ml[KVL];             // 8 KB, mask terms

    const int t    = threadIdx.x;
    const int w    = t >> 6;
    const int wq   = w & 3;           // q subtile
    const int ws   = w >> 2;          // kv half
    const int lane = t & 63;
    const int l31  = lane & 31;
    const int hi   = lane >> 5;

    const int q0 = blockIdx.x * QB;
    const int h  = blockIdx.y, b = blockIdx.z;
    const int bh = b * NH + h;
    const int ws64 = ws * 64;

    constexpr float L2E  = 1.4426950408889634f;
    constexpr float MBIG = 1e9f * L2E;
    constexpr float MOFF = -(1e9f * L2E) - 40.0f * L2E;  // -MBIG - C (static max)

    // ---- Q fragments: q row = q0 + wq*32 + l31; ch halves ----
    const short* qrow = qbf + ((size_t)bh * QL + q0 + wq * 32 + l31) * CH;
    short8 qf0 = *(const short8*)(qrow + hi * 8);
    short8 qf1 = *(const short8*)(qrow + 16 + hi * 8);

    // ---- mask terms -> LDS once per block (512 thr x float4 = 2048) ----
    {
        float4 mv = *(const float4*)(mask + (size_t)b * KVL + t * 4);
        float4 o0 = { fmaf(mv.x, MBIG, MOFF), fmaf(mv.y, MBIG, MOFF),
                      fmaf(mv.z, MBIG, MOFF), fmaf(mv.w, MBIG, MOFF) };
        *(float4*)&Ml[t * 4] = o0;
    }

    // ---- staging addresses: one short8 per thread for K and V ----
    const int rowK = t >> 2, kch = t & 3;
    const short* ksrc = kbf + (size_t)bh * KVL * CH + (size_t)rowK * CH + kch * 8;
    const int kbyte = (rowK * 64 + kch * 16) ^ ((rowK & 7) << 4);
    const int rowV = t >> 4, segV = t & 15;
    const short* vsrc = vtb + (size_t)bh * CH * KVL + (size_t)rowV * KVL + segV * 8;
    const int vbyte = (rowV * 256 + segV * 16) ^ ((rowV & 7) << 4);

    short8 kr0 = *(const short8*)ksrc;          // prefetch strip 0
    short8 vr0 = *(const short8*)vsrc;

    // bias row for this lane's q-row
    const float* brow = bias + ((size_t)h * QL + q0 + wq * 32 + l31) * KVL;

    // prefetch bias for first sub (strip 0, sub ws*2)
    float4 biA[4], biB[4];
    #pragma unroll
    for (int rr = 0; rr < 4; ++rr)
        biA[rr] = *(const float4*)(brow + ws64 + rr * 8 + hi * 4);

    f32x16 O;
    #pragma unroll
    for (int r = 0; r < 16; ++r) O[r] = 0.0f;
    float lp0 = 0.f, lp1 = 0.f, lp2 = 0.f, lp3 = 0.f;

    // One 32-kv subtile. SO32 = kv offset within strip; NEXTCOL = next sub's
    // bias column base (absolute); GUARD = prefetch condition.
    // exp->pack fused per 4-reg group: only 8 packed u32 live, not p[16].
#define SUB_BODY(SO32, BC, BN, NEXTCOL, GUARD)                                 \
    {                                                                          \
        if (GUARD) {                                                           \
            _Pragma("unroll")                                                  \
            for (int rr = 0; rr < 4; ++rr)                                     \
                BN[rr] = *(const float4*)(brow + (NEXTCOL) + rr * 8 + hi * 4); \
        }                                                                      \
        f32x16 Cb;                                                             \
        _Pragma("unroll")                                                      \
        for (int rr = 0; rr < 4; ++rr) {                                       \
            float4 mt = *(const float4*)&Ml[kv0 + (SO32) + rr * 8 + hi * 4];   \
            Cb[4 * rr + 0] = fmaf(BC[rr].x, L2E, mt.x);                        \
            Cb[4 * rr + 1] = fmaf(BC[rr].y, L2E, mt.y);                        \
            Cb[4 * rr + 2] = fmaf(BC[rr].z, L2E, mt.z);                        \
            Cb[4 * rr + 3] = fmaf(BC[rr].w, L2E, mt.w);                        \
        }                                                                      \
        const int krow32 = (SO32) + l31;                                       \
        const int kswz   = (krow32 & 7) << 4;                                  \
        short8 ka0 = *(const short8*)(klb + ((krow32 * 64 + hi * 16) ^ kswz)); \
        short8 ka1 = *(const short8*)(klb + ((krow32 * 64 + 32 + hi * 16) ^ kswz)); \
        __builtin_amdgcn_s_setprio(1);                                         \
        f32x16 S = __builtin_amdgcn_mfma_f32_32x32x16_bf16(ka0, qf0, Cb, 0, 0, 0); \
        S = __builtin_amdgcn_mfma_f32_32x32x16_bf16(ka1, qf1, S, 0, 0, 0);     \
        __builtin_amdgcn_s_setprio(0);                                         \
        unsigned int a1, a2, b1, b2, c1, c2, d1, d2;                           \
        {   float e0 = __builtin_amdgcn_exp2f(S[0]);                           \
            float e1 = __builtin_amdgcn_exp2f(S[1]);                           \
            float e2 = __builtin_amdgcn_exp2f(S[2]);                           \
            float e3 = __builtin_amdgcn_exp2f(S[3]);                           \
            lp0 += e0 + e1;  lp1 += e2 + e3;                                   \
            a1 = pkbf(e0, e1);  a2 = pkbf(e2, e3);  }                          \
        {   float e0 = __builtin_amdgcn_exp2f(S[4]);                           \
            float e1 = __builtin_amdgcn_exp2f(S[5]);                           \
            float e2 = __builtin_amdgcn_exp2f(S[6]);                           \
            float e3 = __builtin_amdgcn_exp2f(S[7]);                           \
            lp0 += e0 + e1;  lp1 += e2 + e3;                                   \
            b1 = pkbf(e0, e1);  b2 = pkbf(e2, e3);  }                          \
        {   float e0 = __builtin_amdgcn_exp2f(S[8]);                           \
            float e1 = __builtin_amdgcn_exp2f(S[9]);                           \
            float e2 = __builtin_amdgcn_exp2f(S[10]);                          \
            float e3 = __builtin_amdgcn_exp2f(S[11]);                          \
            lp2 += e0 + e1;  lp3 += e2 + e3;                                   \
            c1 = pkbf(e0, e1);  c2 = pkbf(e2, e3);  }                          \
        {   float e0 = __builtin_amdgcn_exp2f(S[12]);                          \
            float e1 = __builtin_amdgcn_exp2f(S[13]);                          \
            float e2 = __builtin_amdgcn_exp2f(S[14]);                          \
            float e3 = __builtin_amdgcn_exp2f(S[15]);                          \
            lp2 += e0 + e1;  lp3 += e2 + e3;                                   \
            d1 = pkbf(e0, e1);  d2 = pkbf(e2, e3);  }                          \
        asm("v_permlane32_swap_b32 %0, %1" : "+v"(a1), "+v"(b1));              \
        asm("v_permlane32_swap_b32 %0, %1" : "+v"(a2), "+v"(b2));              \
        asm("v_permlane32_swap_b32 %0, %1" : "+v"(c1), "+v"(d1));              \
        asm("v_permlane32_swap_b32 %0, %1" : "+v"(c2), "+v"(d2));              \
        u32x4 f0v = { a1, a2, b1, b2 };                                        \
        u32x4 f1v = { c1, c2, d1, d2 };                                        \
        short8 pf0 = __builtin_bit_cast(short8, f0v);                          \
        short8 pf1 = __builtin_bit_cast(short8, f1v);                          \
        const int vswz = (l31 & 7) << 4;                                       \
        short8 vf0 = *(const short8*)(vlb + ((l31 * 256 + (SO32) * 2 + hi * 16) ^ vswz)); \
        short8 vf1 = *(const short8*)(vlb + ((l31 * 256 + (SO32) * 2 + 32 + hi * 16) ^ vswz)); \
        __builtin_amdgcn_s_setprio(1);                                         \
        O = __builtin_amdgcn_mfma_f32_32x32x16_bf16(pf0, vf0, O, 0, 0, 0);     \
        O = __builtin_amdgcn_mfma_f32_32x32x16_bf16(pf1, vf1, O, 0, 0, 0);     \
        __builtin_amdgcn_s_setprio(0);                                         \
    }

    #pragma unroll 1
    for (int it = 0; it < NSTRIP; ++it) {
        const int kv0 = it * KVB;
        char* klb = (char*)Kl[it & 1];
        char* vlb = (char*)Vl[it & 1];

        *(short8*)(klb + kbyte) = kr0;
        *(short8*)(vlb + vbyte) = vr0;
        __syncthreads();   // strip staged (also covers Ml on first iteration)

        if (it + 1 < NSTRIP) {
            kr0 = *(const short8*)(ksrc + (size_t)(it + 1) * KVB * CH);
            vr0 = *(const short8*)(vsrc + (it + 1) * KVB);
        }

        // wave (wq,ws) computes subs ws*2 and ws*2+1 of this strip
        SUB_BODY(ws64,      biA, biB, kv0 + ws64 + 32,  1);
        SUB_BODY(ws64 + 32, biB, biA, kv0 + KVB + ws64, (it + 1 < NSTRIP));
    }
#undef SUB_BODY

    // ---- combine the two kv-halves through LDS (reuse Kl/Vl), normalize ----
    float lpq = (lp0 + lp1) + (lp2 + lp3);
    lpq += __shfl_xor(lpq, 32);                 // lane l31 holds l for q=l31 (own half)

    float* Ob = (float*)&Kl[0][0];              // 16 KB: [wq][32 q][32 ch]
    float* Lb = (float*)&Vl[0][0];              // [wq][32]
    __syncthreads();                            // all strip reads done
    if (ws == 1) {
        float* op = Ob + wq * 32 * 32;
        #pragma unroll
        for (int r = 0; r < 16; ++r) {
            int q = (r & 3) + 8 * (r >> 2) + 4 * hi;
            op[q * 32 + l31] = O[r];
        }
        if (lane < 32) Lb[wq * 32 + l31] = lpq;
    }
    __syncthreads();
    if (ws == 0) {
        const float* op = Ob + wq * 32 * 32;
        float ltot = lpq + Lb[wq * 32 + l31];
        float linv = 1.0f / ltot;               // lane l31 <-> q = l31
        short* aop = aob + ((size_t)b * QL + q0 + wq * 32) * DM + h * CH;
        #pragma unroll
        for (int r = 0; r < 16; ++r) {
            int q = (r & 3) + 8 * (r >> 2) + 4 * hi;
            float ov = O[r] + op[q * 32 + l31];
            float inv = __shfl(linv, q);
            aop[(size_t)q * DM + l31] = f2bf(ov * inv);
        }
    }
}

// ---------------------------------------------------------------------------
extern "C" void kernel_launch(void* const* d_in, const int* in_sizes, int n_in,
                              void* d_out, int out_size, void* d_ws, size_t ws_size,
                              hipStream_t stream)
{
    const float* input_q  = (const float*)d_in[0];
    const float* input_kv = (const float*)d_in[1];
    const float* mask     = (const float*)d_in[2];
    const float* bias     = (const float*)d_in[3];
    const float* w_q      = (const float*)d_in[4];
    const float* w_k      = (const float*)d_in[5];
    const float* w_v      = (const float*)d_in[6];
    const float* w_o      = (const float*)d_in[7];
    const float* b_o      = (const float*)d_in[8];
    float* out = (float*)d_out;

    const size_t TOK  = (size_t)B * QL;            // 8192
    const size_t HEAD = (size_t)B * NH * QL * CH;  // 2,097,152 elems

    short* qbf = (short*)d_ws;          // bf16 Q  head-split       4 MB
    short* kbf = qbf + HEAD;            // bf16 K  head-split       4 MB
    short* vtb = kbf + HEAD;            // bf16 V^T head-split      4 MB
    short* aob = vtb + HEAD;            // bf16 attn out [tok][dm]  4 MB
    short* qx  = aob + HEAD;            // bf16 input_q             4 MB
    short* kvx = qx  + HEAD;            // bf16 input_kv            4 MB
    short* wqT = kvx + HEAD;            // bf16 w_q^T  [N][K]       128 KB
    short* wkT = wqT + CQ * DM;
    short* wvT = wkT + CKV * DM;
    short* woT = wvT + CKV * DM;

    dim3 blk(256);
    // 1/sqrt(32) * log2(e): static-max softmax works in exp2 units
    const float qscale = 0.17677669529663687f * 1.4426950408889634f;

    prep_cvt<<<dim3((TOK * CQ / 8 + 255) / 256), blk, 0, stream>>>(input_q,  qx,  (int)(TOK * CQ / 8));
    prep_cvt<<<dim3((TOK * CKV / 8 + 255) / 256), blk, 0, stream>>>(input_kv, kvx, (int)(TOK * CKV / 8));
    prep_wT<<<dim3(DM / 32, CQ / 32),  blk, 0, stream>>>(w_q, wqT, CQ,  DM);
    prep_wT<<<dim3(DM / 32, CKV / 32), blk, 0, stream>>>(w_k, wkT, CKV, DM);
    prep_wT<<<dim3(DM / 32, CKV / 32), blk, 0, stream>>>(w_v, wvT, CKV, DM);
    prep_wT<<<dim3(CQ / 32, DM / 32),  blk, 0, stream>>>(w_o, woT, DM,  CQ);

    dim3 pgrid(DM / 64, TOK / 64);                 // (4, 128)
    gemm_mfma<<<pgrid, blk, 0, stream>>>(qx,  wqT, nullptr, nullptr, qbf,
                                         (int)TOK, DM, CQ,  qscale, 1);
    gemm_mfma<<<pgrid, blk, 0, stream>>>(kvx, wkT, nullptr, nullptr, kbf,
                                         (int)TOK, DM, CKV, 1.0f, 1);
    gemm_mfma<<<pgrid, blk, 0, stream>>>(kvx, wvT, nullptr, nullptr, vtb,
                                         (int)TOK, DM, CKV, 1.0f, 2);

    fattn<<<dim3(QL / QB, NH, B), dim3(512), 0, stream>>>(
        qbf, kbf, vtb, mask, bias, aob);

    gemm_mfma<<<dim3(CQ / 64, TOK / 64), blk, 0, stream>>>(aob, woT, b_o, out, nullptr,
                                         (int)TOK, CQ, DM, 1.0f, 0);
}

// Round 12
// 124.996 us; speedup vs baseline: 1.0035x; 1.0035x over previous
//
#include <hip/hip_runtime.h>
#include <hip/hip_bf16.h>
#include <math.h>

#define B    4
#define QL   2048
#define KVL  2048
#define CQ   256
#define CKV  256
#define CH   32
#define NH   8
#define DM   256   // NH*CH
#define QB   128   // q rows per fattn block (4 q-subtiles x 32)
#define KVB  128   // kv strip per iteration
#define NSTRIP (KVL / KVB)   // 16

typedef __attribute__((ext_vector_type(8)))  short short8;   // 8 x bf16 (4 VGPR)
typedef __attribute__((ext_vector_type(4)))  float f32x4;
typedef __attribute__((ext_vector_type(16))) float f32x16;
typedef __attribute__((ext_vector_type(4)))  unsigned int u32x4;

static __device__ __forceinline__ short f2bf(float x) {
    __hip_bfloat16 h = __float2bfloat16(x);
    return __builtin_bit_cast(short, h);
}
// pack two f32 -> u32 of 2 bf16 (compiler fuses to v_cvt_pk_bf16_f32)
static __device__ __forceinline__ unsigned int pkbf(float lo, float hi) {
    return (unsigned int)(unsigned short)f2bf(lo) |
           ((unsigned int)(unsigned short)f2bf(hi) << 16);
}

// ---------------------------------------------------------------------------
// prep: fp32 -> bf16 copy (8 elems/thread)
// ---------------------------------------------------------------------------
__global__ __launch_bounds__(256) void prep_cvt(
    const float* __restrict__ src, short* __restrict__ dst, int n8)
{
    int i = blockIdx.x * 256 + threadIdx.x;
    if (i >= n8) return;
    const float4* s = (const float4*)src + (size_t)i * 2;
    float4 a = s[0], b = s[1];
    short8 o = { f2bf(a.x), f2bf(a.y), f2bf(a.z), f2bf(a.w),
                 f2bf(b.x), f2bf(b.y), f2bf(b.z), f2bf(b.w) };
    *((short8*)dst + i) = o;
}

// ---------------------------------------------------------------------------
// prep: W [K][N] fp32 -> W^T [N][K] bf16, 32x32 LDS tiles
// ---------------------------------------------------------------------------
__global__ __launch_bounds__(256) void prep_wT(
    const float* __restrict__ w, short* __restrict__ wt, int K, int N)
{
    __shared__ float tile[32][33];
    const int bx = blockIdx.x * 32;            // n
    const int by = blockIdx.y * 32;            // k
    const int tx = threadIdx.x & 31, ty = threadIdx.x >> 5;
    #pragma unroll
    for (int i = 0; i < 32; i += 8)
        tile[ty + i][tx] = w[(size_t)(by + ty + i) * N + bx + tx];
    __syncthreads();
    #pragma unroll
    for (int i = 0; i < 32; i += 8)
        wt[(size_t)(bx + ty + i) * K + by + tx] = f2bf(tile[tx][ty + i]);
}

// ---------------------------------------------------------------------------
// bf16 MFMA GEMM (unchanged): A [M][K] bf16, BT [N][K] bf16.
// 64x64 tile, 4 waves (2x2 of 32x32), BK=32.
// ---------------------------------------------------------------------------
__global__ __launch_bounds__(256) void gemm_mfma(
    const short* __restrict__ A, const short* __restrict__ BT,
    const float* __restrict__ bias, float* __restrict__ outf,
    short* __restrict__ outb,
    int M, int N, int K, float alpha, int mode)
{
    __shared__ __align__(16) short As[64][40];
    __shared__ __align__(16) short Bs[64][40];

    const int t   = threadIdx.x;
    const int m0  = blockIdx.y * 64, n0 = blockIdx.x * 64;
    const int lane = t & 63, w = t >> 6;
    const int c16 = lane & 15, g = lane >> 4;
    const int wm  = (w & 1) * 32, wn = (w >> 1) * 32;
    const int lr  = t >> 2, lc = (t & 3) * 8;

    f32x4 acc[2][2] = {};

    for (int k0 = 0; k0 < K; k0 += 32) {
        __syncthreads();
        *(short8*)&As[lr][lc] = *(const short8*)(A  + (size_t)(m0 + lr) * K + k0 + lc);
        *(short8*)&Bs[lr][lc] = *(const short8*)(BT + (size_t)(n0 + lr) * K + k0 + lc);
        __syncthreads();

        short8 af[2], bf[2];
        #pragma unroll
        for (int i = 0; i < 2; i++) {
            af[i] = *(const short8*)&As[wm + i * 16 + c16][g * 8];
            bf[i] = *(const short8*)&Bs[wn + i * 16 + c16][g * 8];
        }
        #pragma unroll
        for (int i = 0; i < 2; i++)
            #pragma unroll
            for (int j = 0; j < 2; j++)
                acc[i][j] = __builtin_amdgcn_mfma_f32_16x16x32_bf16(af[i], bf[j], acc[i][j], 0, 0, 0);
    }

    #pragma unroll
    for (int i = 0; i < 2; i++) {
        #pragma unroll
        for (int j = 0; j < 2; j++) {
            #pragma unroll
            for (int r = 0; r < 4; r++) {
                int m = m0 + wm + i * 16 + g * 4 + r;
                int n = n0 + wn + j * 16 + c16;
                float v = acc[i][j][r] * alpha;
                if (mode == 0) {
                    outf[(size_t)m * N + n] = v + (bias ? bias[n] : 0.0f);
                } else {
                    int bb = m >> 11, l = m & 2047;
                    int hh = n >> 5,  cc = n & 31;
                    if (mode == 1)
                        outb[(((size_t)bb * NH + hh) * QL + l) * CH + cc] = f2bf(v);
                    else
                        outb[(((size_t)bb * NH + hh) * CH + cc) * (size_t)KVL + l] = f2bf(v);
                }
            }
        }
    }
}

// ---------------------------------------------------------------------------
// Flash attention, R12 = R11 with the VGPR cap ACTUALLY forced:
// amdgpu_waves_per_eu(4, 4) — two-arg form sets min AND max. R11's single-arg
// form was only a minimum; heuristic still targeted 8 waves/EU -> 64 VGPR ->
// spill (+64 MB scratch FETCH, VALUBusy 22%). Grid is 2 blocks/CU so 4
// waves/EU is exactly the reachable occupancy; cap 128 VGPR fits the ~110
// live set with zero spill.
// Structure: intra-block KV-split, 8 waves = 4 q-subtiles x 2 kv-halves,
// 32x32x16 MFMA, swapped QK^T, in-register P (pkbf+permlane32_swap),
// static-max exp2 softmax, bias/mask folded into MFMA C-in.
// D-map (m74/m101): row=(r&3)+8*(r>>2)+4*(lane>>5), col=lane&31.
// ---------------------------------------------------------------------------
__global__ __launch_bounds__(512)
__attribute__((amdgpu_waves_per_eu(4, 4)))
void fattn(
    const short* __restrict__ qbf, const short* __restrict__ kbf,
    const short* __restrict__ vtb, const float* __restrict__ mask,
    const float* __restrict__ bias, short* __restrict__ aob)
{
    __shared__ __align__(16) short Kl[2][KVB * 32];     // 16 KB, swizzled [kv][ch]
    __shared__ __align__(16) short Vl[2][32 * KVB];     // 16 KB, swizzled [ch][kv]
    __shared__ __align__(16) float Ml[KVL];             // 8 KB, mask terms

    const int t    = threadIdx.x;
    const int w    = t >> 6;
    const int wq   = w & 3;           // q subtile
    const int ws   = w >> 2;          // kv half
    const int lane = t & 63;
    const int l31  = lane & 31;
    const int hi   = lane >> 5;

    const int q0 = blockIdx.x * QB;
    const int h  = blockIdx.y, b = blockIdx.z;
    const int bh = b * NH + h;
    const int ws64 = ws * 64;

    constexpr float L2E  = 1.4426950408889634f;
    constexpr float MBIG = 1e9f * L2E;
    constexpr float MOFF = -(1e9f * L2E) - 40.0f * L2E;  // -MBIG - C (static max)

    // ---- Q fragments: q row = q0 + wq*32 + l31; ch halves ----
    const short* qrow = qbf + ((size_t)bh * QL + q0 + wq * 32 + l31) * CH;
    short8 qf0 = *(const short8*)(qrow + hi * 8);
    short8 qf1 = *(const short8*)(qrow + 16 + hi * 8);

    // ---- mask terms -> LDS once per block (512 thr x float4 = 2048) ----
    {
        float4 mv = *(const float4*)(mask + (size_t)b * KVL + t * 4);
        float4 o0 = { fmaf(mv.x, MBIG, MOFF), fmaf(mv.y, MBIG, MOFF),
                      fmaf(mv.z, MBIG, MOFF), fmaf(mv.w, MBIG, MOFF) };
        *(float4*)&Ml[t * 4] = o0;
    }

    // ---- staging addresses: one short8 per thread for K and V ----
    const int rowK = t >> 2, kch = t & 3;
    const short* ksrc = kbf + (size_t)bh * KVL * CH + (size_t)rowK * CH + kch * 8;
    const int kbyte = (rowK * 64 + kch * 16) ^ ((rowK & 7) << 4);
    const int rowV = t >> 4, segV = t & 15;
    const short* vsrc = vtb + (size_t)bh * CH * KVL + (size_t)rowV * KVL + segV * 8;
    const int vbyte = (rowV * 256 + segV * 16) ^ ((rowV & 7) << 4);

    short8 kr0 = *(const short8*)ksrc;          // prefetch strip 0
    short8 vr0 = *(const short8*)vsrc;

    // bias row for this lane's q-row
    const float* brow = bias + ((size_t)h * QL + q0 + wq * 32 + l31) * KVL;

    // prefetch bias for first sub (strip 0, sub ws*2)
    float4 biA[4], biB[4];
    #pragma unroll
    for (int rr = 0; rr < 4; ++rr)
        biA[rr] = *(const float4*)(brow + ws64 + rr * 8 + hi * 4);

    f32x16 O;
    #pragma unroll
    for (int r = 0; r < 16; ++r) O[r] = 0.0f;
    float lp0 = 0.f, lp1 = 0.f, lp2 = 0.f, lp3 = 0.f;

    // One 32-kv subtile. SO32 = kv offset within strip; NEXTCOL = next sub's
    // bias column base (absolute); GUARD = prefetch condition.
    // exp->pack fused per 4-reg group: only 8 packed u32 live, not p[16].
#define SUB_BODY(SO32, BC, BN, NEXTCOL, GUARD)                                 \
    {                                                                          \
        if (GUARD) {                                                           \
            _Pragma("unroll")                                                  \
            for (int rr = 0; rr < 4; ++rr)                                     \
                BN[rr] = *(const float4*)(brow + (NEXTCOL) + rr * 8 + hi * 4); \
        }                                                                      \
        f32x16 Cb;                                                             \
        _Pragma("unroll")                                                      \
        for (int rr = 0; rr < 4; ++rr) {                                       \
            float4 mt = *(const float4*)&Ml[kv0 + (SO32) + rr * 8 + hi * 4];   \
            Cb[4 * rr + 0] = fmaf(BC[rr].x, L2E, mt.x);                        \
            Cb[4 * rr + 1] = fmaf(BC[rr].y, L2E, mt.y);                        \
            Cb[4 * rr + 2] = fmaf(BC[rr].z, L2E, mt.z);                        \
            Cb[4 * rr + 3] = fmaf(BC[rr].w, L2E, mt.w);                        \
        }                                                                      \
        const int krow32 = (SO32) + l31;                                       \
        const int kswz   = (krow32 & 7) << 4;                                  \
        short8 ka0 = *(const short8*)(klb + ((krow32 * 64 + hi * 16) ^ kswz)); \
        short8 ka1 = *(const short8*)(klb + ((krow32 * 64 + 32 + hi * 16) ^ kswz)); \
        __builtin_amdgcn_s_setprio(1);                                         \
        f32x16 S = __builtin_amdgcn_mfma_f32_32x32x16_bf16(ka0, qf0, Cb, 0, 0, 0); \
        S = __builtin_amdgcn_mfma_f32_32x32x16_bf16(ka1, qf1, S, 0, 0, 0);     \
        __builtin_amdgcn_s_setprio(0);                                         \
        unsigned int a1, a2, b1, b2, c1, c2, d1, d2;                           \
        {   float e0 = __builtin_amdgcn_exp2f(S[0]);                           \
            float e1 = __builtin_amdgcn_exp2f(S[1]);                           \
            float e2 = __builtin_amdgcn_exp2f(S[2]);                           \
            float e3 = __builtin_amdgcn_exp2f(S[3]);                           \
            lp0 += e0 + e1;  lp1 += e2 + e3;                                   \
            a1 = pkbf(e0, e1);  a2 = pkbf(e2, e3);  }                          \
        {   float e0 = __builtin_amdgcn_exp2f(S[4]);                           \
            float e1 = __builtin_amdgcn_exp2f(S[5]);                           \
            float e2 = __builtin_amdgcn_exp2f(S[6]);                           \
            float e3 = __builtin_amdgcn_exp2f(S[7]);                           \
            lp0 += e0 + e1;  lp1 += e2 + e3;                                   \
            b1 = pkbf(e0, e1);  b2 = pkbf(e2, e3);  }                          \
        {   float e0 = __builtin_amdgcn_exp2f(S[8]);                           \
            float e1 = __builtin_amdgcn_exp2f(S[9]);                           \
            float e2 = __builtin_amdgcn_exp2f(S[10]);                          \
            float e3 = __builtin_amdgcn_exp2f(S[11]);                          \
            lp2 += e0 + e1;  lp3 += e2 + e3;                                   \
            c1 = pkbf(e0, e1);  c2 = pkbf(e2, e3);  }                          \
        {   float e0 = __builtin_amdgcn_exp2f(S[12]);                          \
            float e1 = __builtin_amdgcn_exp2f(S[13]);                          \
            float e2 = __builtin_amdgcn_exp2f(S[14]);                          \
            float e3 = __builtin_amdgcn_exp2f(S[15]);                          \
            lp2 += e0 + e1;  lp3 += e2 + e3;                                   \
            d1 = pkbf(e0, e1);  d2 = pkbf(e2, e3);  }                          \
        asm("v_permlane32_swap_b32 %0, %1" : "+v"(a1), "+v"(b1));              \
        asm("v_permlane32_swap_b32 %0, %1" : "+v"(a2), "+v"(b2));              \
        asm("v_permlane32_swap_b32 %0, %1" : "+v"(c1), "+v"(d1));              \
        asm("v_permlane32_swap_b32 %0, %1" : "+v"(c2), "+v"(d2));              \
        u32x4 f0v = { a1, a2, b1, b2 };                                        \
        u32x4 f1v = { c1, c2, d1, d2 };                                        \
        short8 pf0 = __builtin_bit_cast(short8, f0v);                          \
        short8 pf1 = __builtin_bit_cast(short8, f1v);                          \
        const int vswz = (l31 & 7) << 4;                                       \
        short8 vf0 = *(const short8*)(vlb + ((l31 * 256 + (SO32) * 2 + hi * 16) ^ vswz)); \
        short8 vf1 = *(const short8*)(vlb + ((l31 * 256 + (SO32) * 2 + 32 + hi * 16) ^ vswz)); \
        __builtin_amdgcn_s_setprio(1);                                         \
        O = __builtin_amdgcn_mfma_f32_32x32x16_bf16(pf0, vf0, O, 0, 0, 0);     \
        O = __builtin_amdgcn_mfma_f32_32x32x16_bf16(pf1, vf1, O, 0, 0, 0);     \
        __builtin_amdgcn_s_setprio(0);                                         \
    }

    #pragma unroll 1
    for (int it = 0; it < NSTRIP; ++it) {
        const int kv0 = it * KVB;
        char* klb = (char*)Kl[it & 1];
        char* vlb = (char*)Vl[it & 1];

        *(short8*)(klb + kbyte) = kr0;
        *(short8*)(vlb + vbyte) = vr0;
        __syncthreads();   // strip staged (also covers Ml on first iteration)

        if (it + 1 < NSTRIP) {
            kr0 = *(const short8*)(ksrc + (size_t)(it + 1) * KVB * CH);
            vr0 = *(const short8*)(vsrc + (it + 1) * KVB);
        }

        // wave (wq,ws) computes subs ws*2 and ws*2+1 of this strip
        SUB_BODY(ws64,      biA, biB, kv0 + ws64 + 32,  1);
        SUB_BODY(ws64 + 32, biB, biA, kv0 + KVB + ws64, (it + 1 < NSTRIP));
    }
#undef SUB_BODY

    // ---- combine the two kv-halves through LDS (reuse Kl/Vl), normalize ----
    float lpq = (lp0 + lp1) + (lp2 + lp3);
    lpq += __shfl_xor(lpq, 32);                 // lane l31 holds l for q=l31 (own half)

    float* Ob = (float*)&Kl[0][0];              // 16 KB: [wq][32 q][32 ch]
    float* Lb = (float*)&Vl[0][0];              // [wq][32]
    __syncthreads();                            // all strip reads done
    if (ws == 1) {
        float* op = Ob + wq * 32 * 32;
        #pragma unroll
        for (int r = 0; r < 16; ++r) {
            int q = (r & 3) + 8 * (r >> 2) + 4 * hi;
            op[q * 32 + l31] = O[r];
        }
        if (lane < 32) Lb[wq * 32 + l31] = lpq;
    }
    __syncthreads();
    if (ws == 0) {
        const float* op = Ob + wq * 32 * 32;
        float ltot = lpq + Lb[wq * 32 + l31];
        float linv = 1.0f / ltot;               // lane l31 <-> q = l31
        short* aop = aob + ((size_t)b * QL + q0 + wq * 32) * DM + h * CH;
        #pragma unroll
        for (int r = 0; r < 16; ++r) {
            int q = (r & 3) + 8 * (r >> 2) + 4 * hi;
            float ov = O[r] + op[q * 32 + l31];
            float inv = __shfl(linv, q);
            aop[(size_t)q * DM + l31] = f2bf(ov * inv);
        }
    }
}

// ---------------------------------------------------------------------------
extern "C" void kernel_launch(void* const* d_in, const int* in_sizes, int n_in,
                              void* d_out, int out_size, void* d_ws, size_t ws_size,
                              hipStream_t stream)
{
    const float* input_q  = (const float*)d_in[0];
    const float* input_kv = (const float*)d_in[1];
    const float* mask     = (const float*)d_in[2];
    const float* bias     = (const float*)d_in[3];
    const float* w_q      = (const float*)d_in[4];
    const float* w_k      = (const float*)d_in[5];
    const float* w_v      = (const float*)d_in[6];
    const float* w_o      = (const float*)d_in[7];
    const float* b_o      = (const float*)d_in[8];
    float* out = (float*)d_out;

    const size_t TOK  = (size_t)B * QL;            // 8192
    const size_t HEAD = (size_t)B * NH * QL * CH;  // 2,097,152 elems

    short* qbf = (short*)d_ws;          // bf16 Q  head-split       4 MB
    short* kbf = qbf + HEAD;            // bf16 K  head-split       4 MB
    short* vtb = kbf + HEAD;            // bf16 V^T head-split      4 MB
    short* aob = vtb + HEAD;            // bf16 attn out [tok][dm]  4 MB
    short* qx  = aob + HEAD;            // bf16 input_q             4 MB
    short* kvx = qx  + HEAD;            // bf16 input_kv            4 MB
    short* wqT = kvx + HEAD;            // bf16 w_q^T  [N][K]       128 KB
    short* wkT = wqT + CQ * DM;
    short* wvT = wkT + CKV * DM;
    short* woT = wvT + CKV * DM;

    dim3 blk(256);
    // 1/sqrt(32) * log2(e): static-max softmax works in exp2 units
    const float qscale = 0.17677669529663687f * 1.4426950408889634f;

    prep_cvt<<<dim3((TOK * CQ / 8 + 255) / 256), blk, 0, stream>>>(input_q,  qx,  (int)(TOK * CQ / 8));
    prep_cvt<<<dim3((TOK * CKV / 8 + 255) / 256), blk, 0, stream>>>(input_kv, kvx, (int)(TOK * CKV / 8));
    prep_wT<<<dim3(DM / 32, CQ / 32),  blk, 0, stream>>>(w_q, wqT, CQ,  DM);
    prep_wT<<<dim3(DM / 32, CKV / 32), blk, 0, stream>>>(w_k, wkT, CKV, DM);
    prep_wT<<<dim3(DM / 32, CKV / 32), blk, 0, stream>>>(w_v, wvT, CKV, DM);
    prep_wT<<<dim3(CQ / 32, DM / 32),  blk, 0, stream>>>(w_o, woT, DM,  CQ);

    dim3 pgrid(DM / 64, TOK / 64);                 // (4, 128)
    gemm_mfma<<<pgrid, blk, 0, stream>>>(qx,  wqT, nullptr, nullptr, qbf,
                                         (int)TOK, DM, CQ,  qscale, 1);
    gemm_mfma<<<pgrid, blk, 0, stream>>>(kvx, wkT, nullptr, nullptr, kbf,
                                         (int)TOK, DM, CKV, 1.0f, 1);
    gemm_mfma<<<pgrid, blk, 0, stream>>>(kvx, wvT, nullptr, nullptr, vtb,
                                         (int)TOK, DM, CKV, 1.0f, 2);

    fattn<<<dim3(QL / QB, NH, B), dim3(512), 0, stream>>>(
        qbf, kbf, vtb, mask, bias, aob);

    gemm_mfma<<<dim3(CQ / 64, TOK / 64), blk, 0, stream>>>(aob, woT, b_o, out, nullptr,
                                         (int)TOK, CQ, DM, 1.0f, 0);
}